// Round 10
// baseline (22.306 us; speedup 1.0000x reference)
//
#include <hip/hip_runtime.h>

#define DDIM   128
#define NS     4            // column slices per relation (R7 sweet spot)
#define SCOL   32           // output columns per block
#define SCH    21           // samples per compute chunk (63 rows + 1 pad)
#define SEGCAP 96

typedef __attribute__((ext_vector_type(8))) short bf16x8;
typedef __attribute__((ext_vector_type(4))) float f32x4;

static __device__ inline unsigned short f2b(float f) {
    unsigned u = __float_as_uint(f);
    u += 0x7fff + ((u >> 16) & 1);      // round-to-nearest-even
    return (unsigned short)(u >> 16);
}

// ---- producer: pack X rows (bf16 dense), W^T (bf16), and write r_e output ----
__global__ __launch_bounds__(256) void pack_kernel(
    const int* __restrict__ h, const int* __restrict__ r,
    const int* __restrict__ pos_t, const int* __restrict__ neg_t,
    const float* __restrict__ ent, const float* __restrict__ rel,
    const float* __restrict__ M, float* __restrict__ out,
    unsigned short* __restrict__ Xp, unsigned short* __restrict__ Wtp,
    int B, int R)
{
    const int bid = blockIdx.x;
    const int t   = threadIdx.x;
    const int XB  = (3 * B) / 16;       // 768 blocks: X rows
    const int WB  = R;                  // 200 blocks: W transpose-convert

    if (bid < XB) {
        // row = sample*3 + v; 16 threads per row, each packs one bf16x8
        const int u   = bid * 256 + t;
        const int row = u >> 4;
        const int kg  = u & 15;
        const int i   = row / 3;
        const int v   = row - 3 * i;
        const int eid = (v == 0) ? h[i] : (v == 1) ? pos_t[i] : neg_t[i];
        const float4 a = *(const float4*)(ent + (size_t)eid * DDIM + kg * 8);
        const float4 b = *(const float4*)(ent + (size_t)eid * DDIM + kg * 8 + 4);
        bf16x8 x;
        x[0] = (short)f2b(a.x); x[1] = (short)f2b(a.y);
        x[2] = (short)f2b(a.z); x[3] = (short)f2b(a.w);
        x[4] = (short)f2b(b.x); x[5] = (short)f2b(b.y);
        x[6] = (short)f2b(b.z); x[7] = (short)f2b(b.w);
        *(bf16x8*)(Xp + (size_t)row * DDIM + kg * 8) = x;
    } else if (bid < XB + WB) {
        // W^T: Wtp[rb][n][k] = bf16(W[k][n])
        const int rb = bid - XB;
        const int g  = t >> 4;          // k-group 0..15
        const int nl = t & 15;
        const float* __restrict__ Wg = M + (size_t)rb * DDIM * DDIM;
        unsigned short* __restrict__ Wo = Wtp + (size_t)rb * DDIM * DDIM;
        #pragma unroll
        for (int i = 0; i < 8; ++i) {
            const int nloc = nl + i * 16;
            bf16x8 w;
            #pragma unroll
            for (int jj = 0; jj < 8; ++jj)
                w[jj] = (short)f2b(Wg[(size_t)(g * 8 + jj) * DDIM + nloc]);
            *(bf16x8*)(Wo + (size_t)nloc * DDIM + g * 8) = w;
        }
    } else {
        // r_e output: out[B*D + i*D + c] = rel[r[i]][c]
        const int u  = (bid - XB - WB) * 256 + t;
        const int i  = u >> 5;
        const int c4 = u & 31;
        const int rr = r[i];
        const float4 v = *(const float4*)(rel + (size_t)rr * DDIM + c4 * 4);
        *(float4*)(out + (size_t)B * DDIM + (size_t)i * DDIM + c4 * 4) = v;
    }
}

// ---- main: scan + MFMA directly from packed global (no LDS data staging) ----
__global__ __launch_bounds__(256) void transr_main(
    const int* __restrict__ r,
    const unsigned short* __restrict__ Xp,
    const unsigned short* __restrict__ Wtp,
    float* __restrict__ out, int B, int R)
{
    const int bid  = blockIdx.x;
    const int rb   = bid % R;          // R%8==0: slices of rb share an XCD
    const int qc   = bid / R;          // 0..3 column slice
    const int t    = threadIdx.x;
    const int wvid = t >> 6;
    const int ln   = t & 63;

    __shared__ int seg[4][SEGCAP];
    __shared__ int wcnt[4];
    __shared__ int list_s[4 * SEGCAP];

    // per-wave int4 ballot scan of one quarter of r[]
    int segn = 0;
    const int qlen4  = B >> 4;         // int4 elems per wave quarter
    const int qbase4 = wvid * qlen4;
    const int4* __restrict__ r4 = (const int4*)r;
    for (int i0 = 0; i0 < qlen4; i0 += 64) {
        const int  e4 = qbase4 + i0 + ln;
        const int4 rv = r4[e4];
        const int  ib = e4 << 2;
        #pragma unroll
        for (int j = 0; j < 4; ++j) {
            const int  rj = (j == 0) ? rv.x : (j == 1) ? rv.y : (j == 2) ? rv.z : rv.w;
            const bool f  = (rj == rb);
            const unsigned long long m = __ballot(f);
            if (f) {
                const int p = segn + __popcll(m & ((1ull << ln) - 1ull));
                if (p < SEGCAP) seg[wvid][p] = ib + j;
            }
            segn += __popcll(m);
        }
    }
    if (ln == 0) wcnt[wvid] = min(segn, SEGCAP);
    __syncthreads();

    const int c0 = wcnt[0], c1 = wcnt[1], c2 = wcnt[2], c3 = wcnt[3];
    const int cum1 = c0, cum2 = c0 + c1, cum3 = c0 + c1 + c2;
    const int cnt  = cum3 + c3;
    if (cnt == 0) return;

    for (int lin = t; lin < cnt; lin += 256) {
        int w, k;
        if      (lin < cum1) { w = 0; k = lin;        }
        else if (lin < cum2) { w = 1; k = lin - cum1; }
        else if (lin < cum3) { w = 2; k = lin - cum2; }
        else                 { w = 3; k = lin - cum3; }
        list_s[lin] = seg[w][k];
    }
    __syncthreads();

    const int lr = ln & 15;
    const int lg = ln >> 4;
    const unsigned short* __restrict__ Wb =
        Wtp + (size_t)rb * DDIM * DDIM + (size_t)(qc * SCOL) * DDIM;

    // hoist B fragments (chunk-invariant): 2 N-tiles x 4 K-steps
    bf16x8 bfr0[4], bfr1[4];
    #pragma unroll
    for (int ks = 0; ks < 4; ++ks) {
        const int kg = ks * 4 + lg;
        bfr0[ks] = *(const bf16x8*)(Wb + (size_t)(0 * 16 + lr) * DDIM + kg * 8);
        bfr1[ks] = *(const bf16x8*)(Wb + (size_t)(1 * 16 + lr) * DDIM + kg * 8);
    }

    const size_t BD = (size_t)B * DDIM;
    for (int ch = 0; ch < cnt; ch += SCH) {
        const int rows_valid = 3 * min(SCH, cnt - ch);

        // A row for this lane (same row across lg; kg varies by lane)
        const int row  = wvid * 16 + lr;
        const int rowg = min(3 * ch + row, 3 * cnt - 1);
        const int jj   = rowg / 3;
        const int v    = rowg - 3 * jj;
        const unsigned short* __restrict__ xa =
            Xp + ((size_t)list_s[jj] * 3 + v) * DDIM;

        f32x4 acc0 = {0.f, 0.f, 0.f, 0.f};
        f32x4 acc1 = {0.f, 0.f, 0.f, 0.f};
        #pragma unroll
        for (int ks = 0; ks < 4; ++ks) {
            const int kg = ks * 4 + lg;
            const bf16x8 a = *(const bf16x8*)(xa + kg * 8);
            acc0 = __builtin_amdgcn_mfma_f32_16x16x32_bf16(a, bfr0[ks], acc0, 0, 0, 0);
            acc1 = __builtin_amdgcn_mfma_f32_16x16x32_bf16(a, bfr1[ks], acc1, 0, 0, 0);
        }

        // epilogue: C layout col=lane&15, row=(lane>>4)*4+reg
        #pragma unroll
        for (int q = 0; q < 4; ++q) {
            const int rowe = wvid * 16 + lg * 4 + q;
            if (rowe < rows_valid) {
                const int rg = 3 * ch + rowe;
                const int j2 = rg / 3;
                const int v2 = rg - 3 * j2;
                const size_t s = (size_t)list_s[j2];
                float* bp = (v2 == 0) ? out : (v2 == 1) ? (out + 2 * BD) : (out + 3 * BD);
                bp[s * DDIM + qc * SCOL + lr]      = acc0[q];
                bp[s * DDIM + qc * SCOL + lr + 16] = acc1[q];
            }
        }
    }
}

extern "C" void kernel_launch(void* const* d_in, const int* in_sizes, int n_in,
                              void* d_out, int out_size, void* d_ws, size_t ws_size,
                              hipStream_t stream) {
    const int*   h     = (const int*)d_in[0];
    const int*   r     = (const int*)d_in[1];
    const int*   pos_t = (const int*)d_in[2];
    const int*   neg_t = (const int*)d_in[3];
    const float* ent   = (const float*)d_in[4];
    const float* rel   = (const float*)d_in[5];
    const float* M     = (const float*)d_in[6];
    float*       out   = (float*)d_out;

    const int B = in_sizes[0];
    const int R = in_sizes[5] / DDIM;

    unsigned short* Xp  = (unsigned short*)d_ws;          // [3*B][128] bf16
    unsigned short* Wtp = Xp + (size_t)3 * B * DDIM;      // [R][128][128] bf16 (W^T)

    const int XB = (3 * B) / 16;      // 768
    const int RB = B / 8;             // 512
    pack_kernel<<<dim3(XB + R + RB), dim3(256), 0, stream>>>(
        h, r, pos_t, neg_t, ent, rel, M, out, Xp, Wtp, B, R);
    transr_main<<<dim3(R * NS), dim3(256), 0, stream>>>(r, Xp, Wtp, out, B, R);
}

// Round 11
// 16.794 us; speedup vs baseline: 1.3282x; 1.3282x over previous
//
#include <hip/hip_runtime.h>

#define DDIM    128
#define NS      4           // column slices per relation (R7 sweet spot)
#define SCOL    32          // output columns per block
#define SCH     21          // samples per compute chunk (63 rows + 1 pad)
#define MROWS   64
#define XSTRIDE 136         // bf16 row stride (272B -> conflict-free b128)
#define WSTRIDE 136
#define SEGCAP  96

typedef __attribute__((ext_vector_type(8))) short bf16x8;
typedef __attribute__((ext_vector_type(4))) float f32x4;

static __device__ inline unsigned short f2b(float f) {
    unsigned u = __float_as_uint(f);
    u += 0x7fff + ((u >> 16) & 1);      // round-to-nearest-even
    return (unsigned short)(u >> 16);
}

__global__ __launch_bounds__(256) void transr_mfma(
    const int* __restrict__ h, const int* __restrict__ r,
    const int* __restrict__ pos_t, const int* __restrict__ neg_t,
    const float* __restrict__ ent, const float* __restrict__ rel,
    const float* __restrict__ M, float* __restrict__ out,
    int B, int R)
{
    const int bid  = blockIdx.x;
    const int rb   = bid % R;          // R%8==0: all slices of rb on one XCD
    const int qc   = bid / R;          // 0..3 column slice
    const int t    = threadIdx.x;
    const int wvid = t >> 6;
    const int ln   = t & 63;

    __shared__ __align__(16) unsigned short Xl[MROWS * XSTRIDE];   // 17.0 KB
    __shared__ __align__(16) unsigned short Wt[SCOL  * WSTRIDE];   // 8.5 KB
    __shared__ int seg[4][SEGCAP];
    __shared__ int wcnt[4];
    __shared__ int list_s[4 * SEGCAP];

    // ---- (1) issue W slice loads into REGISTERS (latency hides under scan) ----
    const int g  = t >> 4;             // 0..15 (k-group)
    const int nl = t & 15;             // 0..15 (local col)
    const float* __restrict__ Wg = M + (size_t)rb * DDIM * DDIM + qc * SCOL;
    float wreg0[8], wreg1[8];
    #pragma unroll
    for (int j = 0; j < 8; ++j) wreg0[j] = Wg[(size_t)(g * 8 + j) * DDIM + nl];
    #pragma unroll
    for (int j = 0; j < 8; ++j) wreg1[j] = Wg[(size_t)(g * 8 + j) * DDIM + nl + 16];

    // ---- (2) per-wave int4 ballot scan of one quarter of r[] ----
    int segn = 0;
    const int qlen4  = B >> 4;         // int4 elems per wave quarter
    const int qbase4 = wvid * qlen4;
    const int4* __restrict__ r4 = (const int4*)r;
    for (int i0 = 0; i0 < qlen4; i0 += 64) {
        const int  e4 = qbase4 + i0 + ln;
        const int4 rv = r4[e4];
        const int  ib = e4 << 2;
        #pragma unroll
        for (int j = 0; j < 4; ++j) {
            const int  rj = (j == 0) ? rv.x : (j == 1) ? rv.y : (j == 2) ? rv.z : rv.w;
            const bool f  = (rj == rb);
            const unsigned long long m = __ballot(f);
            if (f) {
                const int p = segn + __popcll(m & ((1ull << ln) - 1ull));
                if (p < SEGCAP) seg[wvid][p] = ib + j;
            }
            segn += __popcll(m);
        }
    }
    if (ln == 0) wcnt[wvid] = min(segn, SEGCAP);

    // ---- convert W regs -> bf16 LDS (global loads have landed by now) ----
    {
        bf16x8 w0, w1;
        #pragma unroll
        for (int j = 0; j < 8; ++j) { w0[j] = (short)f2b(wreg0[j]); w1[j] = (short)f2b(wreg1[j]); }
        *(bf16x8*)(&Wt[nl * WSTRIDE + g * 8])        = w0;
        *(bf16x8*)(&Wt[(nl + 16) * WSTRIDE + g * 8]) = w1;
    }
    __syncthreads();

    const int c0 = wcnt[0], c1 = wcnt[1], c2 = wcnt[2], c3 = wcnt[3];
    const int cum1 = c0, cum2 = c0 + c1, cum3 = c0 + c1 + c2;
    const int cnt  = cum3 + c3;
    if (cnt == 0) return;

    for (int lin = t; lin < cnt; lin += 256) {
        int w, k;
        if      (lin < cum1) { w = 0; k = lin;        }
        else if (lin < cum2) { w = 1; k = lin - cum1; }
        else if (lin < cum3) { w = 2; k = lin - cum2; }
        else                 { w = 3; k = lin - cum3; }
        list_s[lin] = seg[w][k];
    }
    __syncthreads();

    // ---- (4) hoist B fragments into registers (chunk-invariant) ----
    const int lr = ln & 15;
    const int lg = ln >> 4;
    bf16x8 bfr0[4], bfr1[4];
    #pragma unroll
    for (int ks = 0; ks < 4; ++ks) {
        const int kg = ks * 4 + lg;
        bfr0[ks] = *(const bf16x8*)(&Wt[(0 * 16 + lr) * WSTRIDE + kg * 8]);
        bfr1[ks] = *(const bf16x8*)(&Wt[(1 * 16 + lr) * WSTRIDE + kg * 8]);
    }

    // ---- chunk loop over samples ----
    const size_t BD = (size_t)B * DDIM;
    for (int ch = 0; ch < cnt; ch += SCH) {
        const int rows_valid = 3 * min(SCH, cnt - ch);

        // stage X rows (bf16): 1024 fragments, 4 per thread; clamp pad rows
        for (int lin = t; lin < MROWS * 16; lin += 256) {
            const int row  = lin >> 4;
            const int kg   = lin & 15;
            const int rowg = min(3 * ch + row, 3 * cnt - 1);
            const int jj   = rowg / 3;
            const int v    = rowg - 3 * jj;
            const int sidx = list_s[jj];
            const int eid  = (v == 0) ? h[sidx] : (v == 1) ? pos_t[sidx] : neg_t[sidx];
            const float4 a = *(const float4*)(ent + (size_t)eid * DDIM + kg * 8);
            const float4 b = *(const float4*)(ent + (size_t)eid * DDIM + kg * 8 + 4);
            bf16x8 x;
            x[0] = (short)f2b(a.x); x[1] = (short)f2b(a.y);
            x[2] = (short)f2b(a.z); x[3] = (short)f2b(a.w);
            x[4] = (short)f2b(b.x); x[5] = (short)f2b(b.y);
            x[6] = (short)f2b(b.z); x[7] = (short)f2b(b.w);
            *(bf16x8*)(&Xl[row * XSTRIDE + kg * 8]) = x;
        }
        __syncthreads();

        // ---- MFMA: wave = M-tile, 2 N-tiles x 4 K-steps, B from regs ----
        f32x4 acc0 = {0.f, 0.f, 0.f, 0.f};
        f32x4 acc1 = {0.f, 0.f, 0.f, 0.f};
        #pragma unroll
        for (int ks = 0; ks < 4; ++ks) {
            const int kg = ks * 4 + lg;
            const bf16x8 a = *(const bf16x8*)(&Xl[(wvid * 16 + lr) * XSTRIDE + kg * 8]);
            acc0 = __builtin_amdgcn_mfma_f32_16x16x32_bf16(a, bfr0[ks], acc0, 0, 0, 0);
            acc1 = __builtin_amdgcn_mfma_f32_16x16x32_bf16(a, bfr1[ks], acc1, 0, 0, 0);
        }

        // ---- epilogue: C layout col=lane&15, row=(lane>>4)*4+reg ----
        #pragma unroll
        for (int q = 0; q < 4; ++q) {
            const int rowe = wvid * 16 + lg * 4 + q;
            if (rowe < rows_valid) {
                const int rg = 3 * ch + rowe;
                const int j2 = rg / 3;
                const int v2 = rg - 3 * j2;
                const size_t s = (size_t)list_s[j2];
                float* bp = (v2 == 0) ? out : (v2 == 1) ? (out + 2 * BD) : (out + 3 * BD);
                bp[s * DDIM + qc * SCOL + lr]      = acc0[q];
                bp[s * DDIM + qc * SCOL + lr + 16] = acc1[q];
            }
        }
        __syncthreads();   // protect Xl before next chunk restage
    }

    // ---- (3) r_e gather for this slice (off the critical path) ----
    for (int lin = t; lin < cnt * (SCOL / 4); lin += 256) {
        const int j  = lin >> 3;
        const int c4 = lin & 7;
        const float4 v = *(const float4*)(rel + (size_t)rb * DDIM + qc * SCOL + c4 * 4);
        *(float4*)(out + (size_t)B * DDIM + (size_t)list_s[j] * DDIM + qc * SCOL + c4 * 4) = v;
    }
}

extern "C" void kernel_launch(void* const* d_in, const int* in_sizes, int n_in,
                              void* d_out, int out_size, void* d_ws, size_t ws_size,
                              hipStream_t stream) {
    const int*   h     = (const int*)d_in[0];
    const int*   r     = (const int*)d_in[1];
    const int*   pos_t = (const int*)d_in[2];
    const int*   neg_t = (const int*)d_in[3];
    const float* ent   = (const float*)d_in[4];
    const float* rel   = (const float*)d_in[5];
    const float* M     = (const float*)d_in[6];
    float*       out   = (float*)d_out;

    const int B = in_sizes[0];
    const int R = in_sizes[5] / DDIM;

    transr_mfma<<<dim3(R * NS), dim3(256), 0, stream>>>(
        h, r, pos_t, neg_t, ent, rel, M, out, B, R);
}

// Round 12
// 15.479 us; speedup vs baseline: 1.4411x; 1.0850x over previous
//
#include <hip/hip_runtime.h>

#define DDIM    128
#define NS      4           // column slices per relation
#define SG      2           // sample groups per (relation, slice)
#define SCOL    32          // output columns per block
#define SCH     10          // samples per compute chunk (30 rows <= MROWS)
#define MROWS   32
#define XSTRIDE 136         // bf16 row stride (272B -> conflict-free b128)
#define WSTRIDE 136
#define SEGCAP  96

typedef __attribute__((ext_vector_type(8))) short bf16x8;
typedef __attribute__((ext_vector_type(4))) float f32x4;

static __device__ inline unsigned short f2b(float f) {
    unsigned u = __float_as_uint(f);
    u += 0x7fff + ((u >> 16) & 1);      // round-to-nearest-even
    return (unsigned short)(u >> 16);
}

__global__ __launch_bounds__(256) void transr_mfma(
    const int* __restrict__ h, const int* __restrict__ r,
    const int* __restrict__ pos_t, const int* __restrict__ neg_t,
    const float* __restrict__ ent, const float* __restrict__ rel,
    const float* __restrict__ M, float* __restrict__ out,
    int B, int R)
{
    const int bid  = blockIdx.x;
    const int rb   = bid % R;          // R%8==0: all blocks of rb share an XCD
    const int rest = bid / R;
    const int qc   = rest & (NS - 1);  // 0..3 column slice
    const int sg   = rest >> 2;        // 0..1 sample group
    const int t    = threadIdx.x;
    const int wvid = t >> 6;
    const int ln   = t & 63;

    __shared__ __align__(16) unsigned short Xl[MROWS * XSTRIDE];   // 8.7 KB
    __shared__ __align__(16) unsigned short Wt[SCOL  * WSTRIDE];   // 8.7 KB
    __shared__ int seg[4][SEGCAP];
    __shared__ int wcnt[4];
    __shared__ int list_s[4 * SEGCAP];

    // ---- issue W slice loads into REGISTERS (latency hides under scan) ----
    const int g  = t >> 4;             // 0..15 (k-group)
    const int nl = t & 15;             // 0..15 (local col)
    const float* __restrict__ Wg = M + (size_t)rb * DDIM * DDIM + qc * SCOL;
    float wreg0[8], wreg1[8];
    #pragma unroll
    for (int j = 0; j < 8; ++j) wreg0[j] = Wg[(size_t)(g * 8 + j) * DDIM + nl];
    #pragma unroll
    for (int j = 0; j < 8; ++j) wreg1[j] = Wg[(size_t)(g * 8 + j) * DDIM + nl + 16];

    // ---- per-wave int4 ballot scan of one quarter of r[] ----
    int segn = 0;
    const int qlen4  = B >> 4;
    const int qbase4 = wvid * qlen4;
    const int4* __restrict__ r4 = (const int4*)r;
    for (int i0 = 0; i0 < qlen4; i0 += 64) {
        const int  e4 = qbase4 + i0 + ln;
        const int4 rv = r4[e4];
        const int  ib = e4 << 2;
        #pragma unroll
        for (int j = 0; j < 4; ++j) {
            const int  rj = (j == 0) ? rv.x : (j == 1) ? rv.y : (j == 2) ? rv.z : rv.w;
            const bool f  = (rj == rb);
            const unsigned long long m = __ballot(f);
            if (f) {
                const int p = segn + __popcll(m & ((1ull << ln) - 1ull));
                if (p < SEGCAP) seg[wvid][p] = ib + j;
            }
            segn += __popcll(m);
        }
    }
    if (ln == 0) wcnt[wvid] = min(segn, SEGCAP);

    // ---- convert W regs -> bf16 LDS (global loads landed under scan) ----
    {
        bf16x8 w0, w1;
        #pragma unroll
        for (int j = 0; j < 8; ++j) { w0[j] = (short)f2b(wreg0[j]); w1[j] = (short)f2b(wreg1[j]); }
        *(bf16x8*)(&Wt[nl * WSTRIDE + g * 8])        = w0;
        *(bf16x8*)(&Wt[(nl + 16) * WSTRIDE + g * 8]) = w1;
    }
    __syncthreads();

    const int c0 = wcnt[0], c1 = wcnt[1], c2 = wcnt[2], c3 = wcnt[3];
    const int cum1 = c0, cum2 = c0 + c1, cum3 = c0 + c1 + c2;
    const int cnt  = cum3 + c3;
    if (cnt == 0) return;

    for (int lin = t; lin < cnt; lin += 256) {
        int w, k;
        if      (lin < cum1) { w = 0; k = lin;        }
        else if (lin < cum2) { w = 1; k = lin - cum1; }
        else if (lin < cum3) { w = 2; k = lin - cum2; }
        else                 { w = 3; k = lin - cum3; }
        list_s[lin] = seg[w][k];
    }
    __syncthreads();

    // ---- my sample-group range ----
    const int halfc  = (cnt + 1) >> 1;
    const int gstart = sg * halfc;
    const int gcnt   = max(0, min(cnt - gstart, halfc));

    // ---- r_e gather: sg==0 blocks cover the full slice ----
    if (sg == 0) {
        for (int lin = t; lin < cnt * (SCOL / 4); lin += 256) {
            const int j  = lin >> 3;
            const int c4 = lin & 7;
            const float4 v = *(const float4*)(rel + (size_t)rb * DDIM + qc * SCOL + c4 * 4);
            *(float4*)(out + (size_t)B * DDIM + (size_t)list_s[j] * DDIM + qc * SCOL + c4 * 4) = v;
        }
    }
    if (gcnt == 0) return;

    // ---- hoist this wave's B fragments into registers ----
    const int lr = ln & 15;
    const int lg = ln >> 4;
    const int mt = wvid & 1;           // M-tile (rows mt*16..+15)
    const int nt = wvid >> 1;          // N-tile (cols nt*16..+15)
    bf16x8 bfr[4];
    #pragma unroll
    for (int ks = 0; ks < 4; ++ks) {
        const int kg = ks * 4 + lg;
        bfr[ks] = *(const bf16x8*)(&Wt[(nt * 16 + lr) * WSTRIDE + kg * 8]);
    }

    // ---- chunk loop over my sample group (usually 1 iteration) ----
    const size_t BD = (size_t)B * DDIM;
    for (int ch = 0; ch < gcnt; ch += SCH) {
        const int ccnt = min(SCH, gcnt - ch);
        const int rows_valid = 3 * ccnt;

        // stage only the needed rows (<=30), 16 fragments per row
        for (int lin = t; lin < rows_valid * 16; lin += 256) {
            const int row  = lin >> 4;
            const int kg   = lin & 15;
            const int jj   = row / 3;
            const int v    = row - 3 * jj;
            const int sidx = list_s[gstart + ch + jj];
            const int eid  = (v == 0) ? h[sidx] : (v == 1) ? pos_t[sidx] : neg_t[sidx];
            const float4 a = *(const float4*)(ent + (size_t)eid * DDIM + kg * 8);
            const float4 b = *(const float4*)(ent + (size_t)eid * DDIM + kg * 8 + 4);
            bf16x8 x;
            x[0] = (short)f2b(a.x); x[1] = (short)f2b(a.y);
            x[2] = (short)f2b(a.z); x[3] = (short)f2b(a.w);
            x[4] = (short)f2b(b.x); x[5] = (short)f2b(b.y);
            x[6] = (short)f2b(b.z); x[7] = (short)f2b(b.w);
            *(bf16x8*)(&Xl[row * XSTRIDE + kg * 8]) = x;
        }
        __syncthreads();

        // MFMA: wave (mt,nt), 4 K-steps, B from regs
        f32x4 acc = {0.f, 0.f, 0.f, 0.f};
        #pragma unroll
        for (int ks = 0; ks < 4; ++ks) {
            const int kg = ks * 4 + lg;
            const bf16x8 a = *(const bf16x8*)(&Xl[(mt * 16 + lr) * XSTRIDE + kg * 8]);
            acc = __builtin_amdgcn_mfma_f32_16x16x32_bf16(a, bfr[ks], acc, 0, 0, 0);
        }

        // epilogue: C layout col=lane&15, row=(lane>>4)*4+reg
        #pragma unroll
        for (int q = 0; q < 4; ++q) {
            const int rowe = mt * 16 + lg * 4 + q;
            if (rowe < rows_valid) {
                const int jj = rowe / 3;
                const int v2 = rowe - 3 * jj;
                const size_t s = (size_t)list_s[gstart + ch + jj];
                float* bp = (v2 == 0) ? out : (v2 == 1) ? (out + 2 * BD) : (out + 3 * BD);
                bp[s * DDIM + qc * SCOL + nt * 16 + lr] = acc[q];
            }
        }
        __syncthreads();   // protect Xl before next chunk restage
    }
}

extern "C" void kernel_launch(void* const* d_in, const int* in_sizes, int n_in,
                              void* d_out, int out_size, void* d_ws, size_t ws_size,
                              hipStream_t stream) {
    const int*   h     = (const int*)d_in[0];
    const int*   r     = (const int*)d_in[1];
    const int*   pos_t = (const int*)d_in[2];
    const int*   neg_t = (const int*)d_in[3];
    const float* ent   = (const float*)d_in[4];
    const float* rel   = (const float*)d_in[5];
    const float* M     = (const float*)d_in[6];
    float*       out   = (float*)d_out;

    const int B = in_sizes[0];
    const int R = in_sizes[5] / DDIM;

    transr_mfma<<<dim3(R * NS * SG), dim3(256), 0, stream>>>(
        h, r, pos_t, neg_t, ent, rel, M, out, B, R);
}